// Round 3
// baseline (481.263 us; speedup 1.0000x reference)
//
#include <hip/hip_runtime.h>
#include <cmath>

#define T_SIZE (1u << 19)
#define CB 512                    // coarse Morton bins (3 bits/dim)
#define NBLK 512                  // sort blocks (2048 pts each)
#define RCAP 3584                 // refine LDS point capacity (expected 2048/bin)

typedef _Float16 h8 __attribute__((ext_vector_type(8)));
typedef _Float16 h4 __attribute__((ext_vector_type(4)));
typedef _Float16 h2 __attribute__((ext_vector_type(2)));
typedef float f4 __attribute__((ext_vector_type(4)));

struct Levels {
    float scale[16];
    int   res[16];
    unsigned dense_mask;
};

// softplus(10z)/10, branch-free
__device__ __forceinline__ float softplus10(float z) {
    float e = __builtin_amdgcn_exp2f(fminf(z * 14.426950408889634f, 126.0f)); // e^{10z}
    return __builtin_amdgcn_logf(1.0f + e) * 0.069314718055994531f;
}

// ---------------- Morton helpers --------------------------------------------
__device__ __forceinline__ unsigned spread3(unsigned v) {
    v &= 1023u;
    v = (v | (v << 16)) & 0x030000FFu;
    v = (v | (v << 8))  & 0x0300F00Fu;
    v = (v | (v << 4))  & 0x030C30C3u;
    v = (v | (v << 2))  & 0x09249249u;
    return v;
}

__device__ __forceinline__ unsigned morton_key(float px, float py, float pz) {
    unsigned qx = (unsigned)fminf(fmaxf(px, 0.f) * 32.f, 31.f);
    unsigned qy = (unsigned)fminf(fmaxf(py, 0.f) * 32.f, 31.f);
    unsigned qz = (unsigned)fminf(fmaxf(pz, 0.f) * 32.f, 31.f);
    return (spread3(qx) << 2) | (spread3(qy) << 1) | spread3(qz);  // 15 bits
}

// -------- Kernel 0: table f32->f16 + weights f32->f16 + FUSED hist ----------
// Extra NBLK blocks past the convert range do the Morton coarse histogram
// (overlaps the BW-bound convert; hides hist entirely).
__global__ __launch_bounds__(256) void convert_kernel(
    const float2* __restrict__ t, h2* __restrict__ o, int total4,
    const float* __restrict__ w1, const float* __restrict__ w2,
    const float* __restrict__ w3, _Float16* __restrict__ wh,
    const float* __restrict__ xs, unsigned short* __restrict__ M, int N)
{
    const int histStart = (total4 + 10240 + 255) >> 8;
    if ((int)blockIdx.x >= histStart) {
        __shared__ unsigned h[CB];
        const int blk = blockIdx.x - histStart;
        for (int t2 = threadIdx.x; t2 < CB; t2 += 256) h[t2] = 0u;
        __syncthreads();
        const int s = blk * 2048;
#pragma unroll
        for (int j = 0; j < 8; ++j) {
            int i = s + threadIdx.x + j * 256;
            unsigned k = morton_key(xs[3 * i], xs[3 * i + 1], xs[3 * i + 2]) >> 6;
            atomicAdd(&h[k], 1u);              // LDS atomic
        }
        __syncthreads();
        for (int t2 = threadIdx.x; t2 < CB; t2 += 256)
            M[t2 * NBLK + blk] = (unsigned short)h[t2];
        return;
    }
    int i = blockIdx.x * 256 + threadIdx.x;
    if (i < total4) {
        const float2* src = t + (size_t)i * 4;
        h8 r;
#pragma unroll
        for (int j = 0; j < 4; ++j) {
            float2 v = src[j];
            r[2 * j]     = (_Float16)v.x;
            r[2 * j + 1] = (_Float16)v.y;
        }
        *(h8*)(o + (size_t)i * 4) = r;
    } else {
        int k = i - total4;                    // 40 extra blocks: 10240 weights
        if (k < 10240) {
            float v = (k < 2048) ? w1[k] : (k < 6144) ? w2[k - 2048] : w3[k - 6144];
            wh[k] = (_Float16)v;
        }
    }
}

// one block: exclusive scan of CB*NBLK = 262144 counters (bin-major flattened)
__global__ __launch_bounds__(1024) void scan_kernel(
    const unsigned short* __restrict__ M, unsigned* __restrict__ Ms)
{
    __shared__ unsigned tmp[1024];
    const int t = threadIdx.x;
    const int PERS = (CB * NBLK) / 1024;       // 256
    unsigned s = 0;
    for (int j = 0; j < PERS; ++j) s += M[t * PERS + j];
    tmp[t] = s;
    __syncthreads();
    for (int d = 1; d < 1024; d <<= 1) {
        unsigned v = (t >= d) ? tmp[t - d] : 0u;
        __syncthreads();
        tmp[t] += v;
        __syncthreads();
    }
    unsigned run = (t > 0) ? tmp[t - 1] : 0u;
    for (int j = 0; j < PERS; ++j) {
        unsigned v = M[t * PERS + j];
        Ms[t * PERS + j] = run;
        run += v;
    }
}

// coarse scatter with LOCAL LDS SORT: block counting-sorts its 2048 points in
// LDS, then writes out in sorted order -> stores become ~512 monotone 64B runs
// (~16-20 lines/wave) instead of 64 random lines/wave (the round-2 cost).
__global__ __launch_bounds__(256) void cscatter_kernel(
    const float* __restrict__ xs, const unsigned* __restrict__ Ms,
    float4* __restrict__ sx4, int N)
{
    __shared__ float4  pts[2048];              // 32KB sorted points
    __shared__ unsigned gp[2048];              // 8KB global positions
    __shared__ unsigned lh[CB];                // hist, then cursors
    __shared__ unsigned lbase[CB];
    __shared__ unsigned tmp[256];
    const int tid = threadIdx.x;
    const int blk = blockIdx.x;
    for (int t2 = tid; t2 < CB; t2 += 256) lh[t2] = 0u;
    __syncthreads();
    const int s = blk * 2048;
    float4  myp[8];
    unsigned myk[8];
#pragma unroll
    for (int j = 0; j < 8; ++j) {
        int i = s + tid + j * 256;
        float px = xs[3 * i], py = xs[3 * i + 1], pz = xs[3 * i + 2];
        myp[j] = make_float4(px, py, pz, __uint_as_float((unsigned)i));
        myk[j] = morton_key(px, py, pz) >> 6;
        atomicAdd(&lh[myk[j]], 1u);
    }
    __syncthreads();
    // exclusive scan of lh[512] (2 bins/thread) -> lbase
    unsigned a0 = lh[2 * tid], a1 = lh[2 * tid + 1];
    tmp[tid] = a0 + a1;
    __syncthreads();
    for (int d = 1; d < 256; d <<= 1) {
        unsigned v = (tid >= d) ? tmp[tid - d] : 0u;
        __syncthreads();
        tmp[tid] += v;
        __syncthreads();
    }
    unsigned eb = (tid > 0) ? tmp[tid - 1] : 0u;
    lbase[2 * tid] = eb;
    lbase[2 * tid + 1] = eb + a0;
    __syncthreads();
    lh[2 * tid] = 0u; lh[2 * tid + 1] = 0u;    // reset as cursors
    __syncthreads();
#pragma unroll
    for (int j = 0; j < 8; ++j) {
        unsigned k = myk[j];
        unsigned r = atomicAdd(&lh[k], 1u);
        unsigned slot = lbase[k] + r;
        pts[slot] = myp[j];
        gp[slot] = Ms[k * NBLK + blk] + r;
    }
    __syncthreads();
    for (int j = tid; j < 2048; j += 256)
        sx4[gp[j]] = pts[j];                   // monotone, run-coalesced
}

// one block per coarse bin: in-place sort of its segment by low 6 Morton bits
// (restores the full 15-bit sorted order). Overflow -> skip (perf-only).
__global__ __launch_bounds__(256) void refine_kernel(
    float4* __restrict__ sx4, const unsigned* __restrict__ Ms, int N)
{
    __shared__ float4 pts[RCAP];
    __shared__ unsigned h[64], base[64];
    const int b = blockIdx.x;
    const unsigned s = Ms[b * NBLK];
    const unsigned e = (b == CB - 1) ? (unsigned)N : Ms[(b + 1) * NBLK];
    const unsigned cnt = e - s;
    if (cnt > RCAP) return;                    // block-uniform: safe
    if (threadIdx.x < 64) h[threadIdx.x] = 0u;
    __syncthreads();
    for (unsigned i = threadIdx.x; i < cnt; i += 256) {
        float4 q = sx4[s + i];
        pts[i] = q;
        unsigned k = morton_key(q.x, q.y, q.z) & 63u;
        atomicAdd(&h[k], 1u);
    }
    __syncthreads();
    if (threadIdx.x == 0) {
        unsigned a = 0;
        for (int j = 0; j < 64; ++j) { base[j] = a; a += h[j]; }
    }
    __syncthreads();
    if (threadIdx.x < 64) h[threadIdx.x] = 0u;
    __syncthreads();
    for (unsigned i = threadIdx.x; i < cnt; i += 256) {
        float4 q = pts[i];
        unsigned k = morton_key(q.x, q.y, q.z) & 63u;
        unsigned r = base[k] + atomicAdd(&h[k], 1u);
        sx4[s + r] = q;                        // stores land in hot 32KB window
    }
}

// Two-corner gather. When hash/dense indices form an aligned pair (i0^i1==1,
// ~1/2 of corners: even cx always maps to adjacent hashes since x-prime==1),
// ONE aligned 8B load covers both corners; else two 4B loads.
// 1.5 lines/pair avg vs 1.625 for the old 16B-group trick.
__device__ __forceinline__ void gather_pair(
    const h2* __restrict__ tl, unsigned i0, unsigned i1,
    float2& v0, float2& v1)
{
    unsigned e0, e1;
    if ((i0 ^ i1) == 1u) {
        uint2 both = *(const uint2*)(tl + (i0 & ~1u));   // aligned 8B
        e0 = (i0 & 1u) ? both.y : both.x;
        e1 = (i0 & 1u) ? both.x : both.y;
    } else {
        e0 = *(const unsigned*)(tl + i0);
        e1 = *(const unsigned*)(tl + i1);
    }
    h2 c0 = __builtin_bit_cast(h2, e0);
    h2 c1 = __builtin_bit_cast(h2, e1);
    v0 = make_float2((float)c0[0], (float)c0[1]);
    v1 = make_float2((float)c1[0], (float)c1[1]);
}

// full per-(point,level) encode -> packed h2 feature pair
__device__ __forceinline__ h2 encode_point(
    float px, float py, float pz, float s, int res, bool dense,
    const h2* __restrict__ tl)
{
    float fx = px * s + 0.5f, fy = py * s + 0.5f, fz = pz * s + 0.5f;
    float gx = floorf(fx), gy = floorf(fy), gz = floorf(fz);
    float wx = fx - gx, wy = fy - gy, wz = fz - gz;
    int cx = (int)gx, cy = (int)gy, cz = (int)gz;

    float2 vx0[4], vx1[4];             // combo j: y=(j>>1), z=(j&1)
    if (dense) {
        int r1 = res - 1;
        int x0 = min(cx, r1), x1 = min(cx + 1, r1);
        int y0 = min(cy, r1), y1 = min(cy + 1, r1);
        int z0 = min(cz, r1), z1 = min(cz + 1, r1);
        int rr = res * res;
        int bases[4] = {y0 * res + z0 * rr, y0 * res + z1 * rr,
                        y1 * res + z0 * rr, y1 * res + z1 * rr};
#pragma unroll
        for (int j = 0; j < 4; ++j)
            gather_pair(tl, (unsigned)(x0 + bases[j]), (unsigned)(x1 + bases[j]),
                        vx0[j], vx1[j]);
    } else {
        unsigned hy0 = (unsigned)cy * 2654435761u, hy1 = (unsigned)(cy + 1) * 2654435761u;
        unsigned hz0 = (unsigned)cz * 805459861u,  hz1 = (unsigned)(cz + 1) * 805459861u;
        unsigned Y[4] = {hy0 ^ hz0, hy0 ^ hz1, hy1 ^ hz0, hy1 ^ hz1};
        const unsigned M = T_SIZE - 1;
#pragma unroll
        for (int j = 0; j < 4; ++j)
            gather_pair(tl, ((unsigned)cx ^ Y[j]) & M,
                        ((unsigned)(cx + 1) ^ Y[j]) & M, vx0[j], vx1[j]);
    }

    float wx0 = 1.f - wx, wy0 = 1.f - wy, wz0 = 1.f - wz;
    float wyz[4] = {wy0 * wz0, wy0 * wz, wy * wz0, wy * wz};
    float f0 = 0.f, f1 = 0.f;
#pragma unroll
    for (int j = 0; j < 4; ++j) {
        float w0 = wx0 * wyz[j], w1 = wx * wyz[j];
        f0 += w0 * vx0[j].x + w1 * vx1[j].x;
        f1 += w0 * vx0[j].y + w1 * vx1[j].y;
    }
    h2 r; r[0] = (_Float16)f0; r[1] = (_Float16)f1;
    return r;
}

// ---------------- Kernel A (phase 1): hash levels lbase.. -> enc2 [16][N] ----
// grid (4096, nLevels), y slow-varying -> 1-2 levels hot -> L2-resident tables.
__global__ __launch_bounds__(256) void encode_kernel(
    const float* __restrict__ xs, const h2* __restrict__ table,
    h2* __restrict__ enc2, Levels lv, int lbase, int N)
{
    __shared__ float sx[768];
    const int i0 = blockIdx.x * 256;
    for (int t = threadIdx.x; t < 768; t += 256) sx[t] = xs[(size_t)i0 * 3 + t];
    __syncthreads();

    const int l = lbase + blockIdx.y;
    const int i = i0 + threadIdx.x;
    if (i >= N) return;
    h2 r = encode_point(sx[threadIdx.x * 3], sx[threadIdx.x * 3 + 1],
                        sx[threadIdx.x * 3 + 2], lv.scale[l], lv.res[l],
                        (lv.dense_mask >> l) & 1u, table + (size_t)l * T_SIZE);
    enc2[(size_t)l * N + i] = r;       // coalesced 4B store
}

// sorted variant: one coalesced 16B load per point; Morton order makes wave
// gathers line-share (x-prime==1 -> adjacent cx share lines).
__global__ __launch_bounds__(256) void encode_kernel_sorted(
    const float4* __restrict__ xs4, const h2* __restrict__ table,
    h2* __restrict__ enc2, Levels lv, int lbase, int N)
{
    const int i = blockIdx.x * 256 + threadIdx.x;
    if (i >= N) return;
    const int l = lbase + blockIdx.y;
    float4 q = xs4[i];
    h2 r = encode_point(q.x, q.y, q.z, lv.scale[l], lv.res[l],
                        (lv.dense_mask >> l) & 1u, table + (size_t)l * T_SIZE);
    enc2[(size_t)l * N + i] = r;       // coalesced 4B store
}

// generic 8-half fragment load (f16 direct dwordx4, or f32 + convert)
template <typename WT>
__device__ __forceinline__ h8 load_frag8(const WT* p) {
    if constexpr (sizeof(WT) == 2) {
        return *(const h8*)p;
    } else {
        h8 r;
#pragma unroll
        for (int j = 0; j < 8; ++j) r[j] = (_Float16)p[j];
        return r;
    }
}

// ------------- Kernel B (fused): encode levels {0-4,15} locally + MLP -------
// Small-table levels (3.3MB total, L2-resident at ANY ordering) are encoded
// per-block into wave-private LDS (never touch global enc2); 10 hash levels
// staged coalesced from enc2. Gather-bound encode overlaps MFMA/VALU MLP
// across resident blocks. sEnc(4KB/wave) unioned under sAct(9216B/wave);
// layer-1 B-frags pre-read to regs before sAct clobbers. One barrier total.
// A[m=lane&15][k=quad*8+j]; B[k=quad*8+j][n=lane&15]; D[row=quad*4+r][col=lane&15].
// SORTED: points come as float4{x,y,z,bitcast(orig)}; result scattered to out[orig].
template <typename WT, bool LOCAL, bool SORTED>
__global__ __launch_bounds__(256, 3) void fused_kernel(
    const float* __restrict__ xs, const float4* __restrict__ xs4,
    const h2* __restrict__ table16, const h2* __restrict__ enc2,
    const WT* __restrict__ w1, const WT* __restrict__ w2,
    const WT* __restrict__ w3, const float* __restrict__ w4,
    float* __restrict__ out, Levels lv, int N)
{
    constexpr int AR = 72;                          // 144B act rows, 16B-aligned
    __shared__ __align__(16) char smem[4 * 9216];   // per-wave: sEnc ∪ sAct
    __shared__ float sx[768];

    const int tid  = threadIdx.x;
    const int wave = tid >> 6;
    const int lane = tid & 63;
    const int lrow = lane & 15;
    const int quad = lane >> 4;
    const int base = blockIdx.x * 256;
    char* wmem = smem + wave * 9216;
    const f4 zero = {0.f, 0.f, 0.f, 0.f};

    float px, py, pz;
    unsigned oi = 0;
    if constexpr (SORTED) {
        float4 q = xs4[base + tid];
        px = q.x; py = q.y; pz = q.z;
        oi = __float_as_uint(q.w);
    } else {
        for (int t = tid; t < 768; t += 256) sx[t] = xs[(size_t)base * 3 + t];
        __syncthreads();
        px = sx[tid * 3]; py = sx[tid * 3 + 1]; pz = sx[tid * 3 + 2];
    }
    const int p = tid & 63;                         // local point in wave region

    // sEnc layout (transposed): byte = (l>>2)*1024 + p*16 + (l&3)*4  (2-way banks)
    if (LOCAL) {
#pragma unroll
        for (int l = 5; l < 15; ++l) {              // 10 coalesced 4B global loads
            h2 v = enc2[(size_t)l * N + base + tid];
            *(h2*)(wmem + ((l >> 2) << 10) + (p << 4) + ((l & 3) << 2)) = v;
        }
        const int LMAP[6] = {0, 1, 2, 3, 4, 15};    // tables sum 3.3MB: L2-safe
#pragma unroll 2
        for (int s6 = 0; s6 < 6; ++s6) {
            const int l = LMAP[s6];
            h2 v = encode_point(px, py, pz, lv.scale[l], lv.res[l],
                                (lv.dense_mask >> l) & 1u,
                                table16 + (size_t)l * T_SIZE);
            *(h2*)(wmem + ((l >> 2) << 10) + (p << 4) + ((l & 3) << 2)) = v;
        }
    } else {
#pragma unroll
        for (int l = 0; l < 16; ++l) {
            h2 v = enc2[(size_t)l * N + base + tid];
            *(h2*)(wmem + ((l >> 2) << 10) + (p << 4) + ((l & 3) << 2)) = v;
        }
    }

    asm volatile("" ::: "memory");   // keep weight loads after encode (pressure)

    // weight A-frags (L2-hot) + packed w4
    h8 aW1[4];
#pragma unroll
    for (int tm = 0; tm < 4; ++tm)
        aW1[tm] = load_frag8(w1 + (tm * 16 + lrow) * 32 + quad * 8);
    h8 aW2[4][2], aW3[4][2];
#pragma unroll
    for (int tm = 0; tm < 4; ++tm)
#pragma unroll
        for (int km = 0; km < 2; ++km) {
            aW2[tm][km] = load_frag8(w2 + (tm * 16 + lrow) * 64 + km * 32 + quad * 8);
            aW3[tm][km] = load_frag8(w3 + (tm * 16 + lrow) * 64 + km * 32 + quad * 8);
        }
    h4 w4q[4];
#pragma unroll
    for (int tm = 0; tm < 4; ++tm)
#pragma unroll
        for (int r = 0; r < 4; ++r) w4q[tm][r] = (_Float16)w4[tm * 16 + quad * 4 + r];

    // pre-read ALL layer-1 B-frags (wave-private rows; same-wave LDS ordering)
    // BEFORE sAct overwrites the sEnc region.
    h8 bin[4];
#pragma unroll
    for (int t = 0; t < 4; ++t)
        bin[t] = *(const h8*)(wmem + (quad << 10) + ((t * 16 + lrow) << 4));

    _Float16* wAct = (_Float16*)wmem;               // local rows 0..63, stride AR

    // ---- Layer 1: D1 = W1 · enc^T ----
#pragma unroll
    for (int t = 0; t < 4; ++t) {
        const int arow = (t * 16 + lrow) * AR;
#pragma unroll
        for (int tm = 0; tm < 4; ++tm) {
            f4 acc = __builtin_amdgcn_mfma_f32_16x16x32_f16(aW1[tm], bin[t], zero, 0, 0, 0);
            h4 pk;
#pragma unroll
            for (int r = 0; r < 4; ++r) pk[r] = (_Float16)softplus10(acc[r]);
            *(h4*)&wAct[arow + tm * 16 + quad * 4] = pk;
        }
    }

    // ---- Layer 2: D2 = W2 · act1^T ----
#pragma unroll
    for (int t = 0; t < 4; ++t) {
        const int arow = (t * 16 + lrow) * AR;
        h8 b0 = *(const h8*)&wAct[arow + quad * 8];
        h8 b1 = *(const h8*)&wAct[arow + 32 + quad * 8];
        f4 accs[4];
#pragma unroll
        for (int tm = 0; tm < 4; ++tm) {
            f4 acc = __builtin_amdgcn_mfma_f32_16x16x32_f16(aW2[tm][0], b0, zero, 0, 0, 0);
            acc     = __builtin_amdgcn_mfma_f32_16x16x32_f16(aW2[tm][1], b1, acc,  0, 0, 0);
            accs[tm] = acc;
        }
#pragma unroll
        for (int tm = 0; tm < 4; ++tm) {
            h4 pk;
#pragma unroll
            for (int r = 0; r < 4; ++r) pk[r] = (_Float16)softplus10(accs[tm][r]);
            *(h4*)&wAct[arow + tm * 16 + quad * 4] = pk;
        }
    }

    // ---- Layer 3+4 fused: sdf = w4 · softplus(W3 · act2^T) ----
#pragma unroll
    for (int t = 0; t < 4; ++t) {
        const int arow = (t * 16 + lrow) * AR;
        h8 b0 = *(const h8*)&wAct[arow + quad * 8];
        h8 b1 = *(const h8*)&wAct[arow + 32 + quad * 8];
        float sum = 0.f;
#pragma unroll
        for (int tm = 0; tm < 4; ++tm) {
            f4 acc = __builtin_amdgcn_mfma_f32_16x16x32_f16(aW3[tm][0], b0, zero, 0, 0, 0);
            acc     = __builtin_amdgcn_mfma_f32_16x16x32_f16(aW3[tm][1], b1, acc,  0, 0, 0);
#pragma unroll
            for (int r = 0; r < 4; ++r)
                sum += (float)w4q[tm][r] * softplus10(acc[r]);
        }
        sum += __shfl_xor(sum, 16, 64);
        sum += __shfl_xor(sum, 32, 64);
        if constexpr (SORTED) {
            // orig index of output row (t*16+lrow) lives in that lane's reg
            unsigned t_oi = __shfl(oi, t * 16 + lrow, 64);
            if (quad == 0) out[t_oi] = sum;
        } else {
            if (quad == 0)
                out[base + wave * 64 + t * 16 + lrow] = sum;
        }
    }
}

// Fallback encode (f32 table, all 16 levels) if workspace too small
__global__ __launch_bounds__(256) void encode_kernel_f32(
    const float* __restrict__ xs, const float2* __restrict__ table,
    h2* __restrict__ enc2, Levels lv, int N)
{
    const int i = blockIdx.x * 256 + threadIdx.x;
    const int l = blockIdx.y;
    if (i >= N) return;
    float px = xs[3 * i], py = xs[3 * i + 1], pz = xs[3 * i + 2];
    float s = lv.scale[l];
    int res = lv.res[l];
    float fx = px * s + 0.5f, fy = py * s + 0.5f, fz = pz * s + 0.5f;
    float gx = floorf(fx), gy = floorf(fy), gz = floorf(fz);
    float wx = fx - gx, wy = fy - gy, wz = fz - gz;
    int cx = (int)gx, cy = (int)gy, cz = (int)gz;
    unsigned idx[8];
    if ((lv.dense_mask >> l) & 1u) {
        int r1 = res - 1;
        int x0 = min(cx, r1), x1 = min(cx + 1, r1);
        int y0 = min(cy, r1), y1 = min(cy + 1, r1);
        int z0 = min(cz, r1), z1 = min(cz + 1, r1);
        int rr = res * res;
        idx[0] = x0 + y0 * res + z0 * rr; idx[1] = x0 + y0 * res + z1 * rr;
        idx[2] = x0 + y1 * res + z0 * rr; idx[3] = x0 + y1 * res + z1 * rr;
        idx[4] = x1 + y0 * res + z0 * rr; idx[5] = x1 + y0 * res + z1 * rr;
        idx[6] = x1 + y1 * res + z0 * rr; idx[7] = x1 + y1 * res + z1 * rr;
    } else {
        unsigned hx0 = (unsigned)cx, hx1 = (unsigned)(cx + 1);
        unsigned hy0 = (unsigned)cy * 2654435761u, hy1 = (unsigned)(cy + 1) * 2654435761u;
        unsigned hz0 = (unsigned)cz * 805459861u,  hz1 = (unsigned)(cz + 1) * 805459861u;
        idx[0] = (hx0^hy0^hz0) & (T_SIZE-1); idx[1] = (hx0^hy0^hz1) & (T_SIZE-1);
        idx[2] = (hx0^hy1^hz0) & (T_SIZE-1); idx[3] = (hx0^hy1^hz1) & (T_SIZE-1);
        idx[4] = (hx1^hy0^hz0) & (T_SIZE-1); idx[5] = (hx1^hy0^hz1) & (T_SIZE-1);
        idx[6] = (hx1^hy1^hz0) & (T_SIZE-1); idx[7] = (hx1^hy1^hz1) & (T_SIZE-1);
    }
    const float2* tl = table + (size_t)l * T_SIZE;
    float wx0 = 1.f - wx, wy0 = 1.f - wy, wz0 = 1.f - wz;
    float wcs[8] = {wx0*wy0*wz0, wx0*wy0*wz, wx0*wy*wz0, wx0*wy*wz,
                    wx*wy0*wz0,  wx*wy0*wz,  wx*wy*wz0,  wx*wy*wz};
    float f0 = 0.f, f1 = 0.f;
#pragma unroll
    for (int c = 0; c < 8; ++c) {
        float2 v = tl[idx[c]];
        f0 += wcs[c] * v.x; f1 += wcs[c] * v.y;
    }
    h2 r; r[0] = (_Float16)f0; r[1] = (_Float16)f1;
    enc2[(size_t)l * N + i] = r;
}

extern "C" void kernel_launch(void* const* d_in, const int* in_sizes, int n_in,
                              void* d_out, int out_size, void* d_ws, size_t ws_size,
                              hipStream_t stream) {
    const float* x     = (const float*)d_in[0];
    const float* table = (const float*)d_in[1];
    const float* w1    = (const float*)d_in[2];
    const float* w2    = (const float*)d_in[3];
    const float* w3    = (const float*)d_in[4];
    const float* w4    = (const float*)d_in[5];
    float* out = (float*)d_out;
    const int N = in_sizes[0] / 3;                 // 1<<20

    Levels lv;
    lv.dense_mask = 0;
    const double pls = exp2(log2(2048.0 / 16.0) / 15.0);
    const double lg  = log2(pls);
    for (int l = 0; l < 16; ++l) {
        double sc = exp2((double)l * lg) * 16.0 - 1.0;
        int res = (int)ceil(sc) + 1;
        lv.scale[l] = (float)sc;
        lv.res[l]   = res;
        if ((long long)res * res * res <= (long long)T_SIZE) lv.dense_mask |= (1u << l);
    }

    const size_t encBytes   = (size_t)16 * N * 4;        // 64 MB ([16][N] h2)
    const size_t tableBytes = (size_t)16 * T_SIZE * 4;   // 33.5 MB f16 table
    const size_t whBytes    = 32768;                     // 10240 f16 weights
    const size_t sx4Bytes   = (size_t)N * 16;            // 16 MB sorted float4
    h2* enc2 = (h2*)d_ws;

    const int ptBlocks = (N + 255) / 256;                // 4096

    if (ws_size >= encBytes + tableBytes + whBytes + sx4Bytes
        && N == NBLK * 2048) {
        h2* table16    = (h2*)((char*)d_ws + encBytes);
        _Float16* wh   = (_Float16*)((char*)d_ws + encBytes + tableBytes);
        float4* sx4    = (float4*)((char*)d_ws + encBytes + tableBytes + whBytes);
        // M/Ms live inside enc2's level-0..4 region (20MB, never written in
        // this branch: fused computes levels 0-4 & 15 locally, encode writes
        // only 5..14, and the sort completes before encode launches).
        unsigned short* M = (unsigned short*)d_ws;                       // 512KB
        unsigned* Ms      = (unsigned*)((char*)d_ws + 1024 * 1024);      // 1MB

        const int total4 = 16 * T_SIZE / 4;              // 2,097,152
        const int convBlocks = (total4 + 10240 + 255) / 256;
        // convert + fused hist (extra NBLK blocks)
        hipLaunchKernelGGL(convert_kernel, dim3(convBlocks + NBLK), dim3(256), 0,
                           stream, (const float2*)table, table16, total4,
                           w1, w2, w3, wh, x, M, N);
        hipLaunchKernelGGL(scan_kernel, dim3(1), dim3(1024), 0, stream, M, Ms);
        hipLaunchKernelGGL(cscatter_kernel, dim3(NBLK), dim3(256), 0, stream,
                           x, Ms, sx4, N);
        hipLaunchKernelGGL(refine_kernel, dim3(CB), dim3(256), 0, stream,
                           sx4, Ms, N);

        // phase 1: hash levels 5..14, level-major, sorted points
        hipLaunchKernelGGL(encode_kernel_sorted, dim3(ptBlocks, 10), dim3(256), 0, stream,
                           (const float4*)sx4, (const h2*)table16, enc2, lv, 5, N);
        // phase 2: fused local-encode {0-4,15} + MLP, scatter to out[orig]
        hipLaunchKernelGGL((fused_kernel<_Float16, true, true>), dim3(ptBlocks), dim3(256),
                           0, stream, x, (const float4*)sx4, (const h2*)table16,
                           (const h2*)enc2, wh, wh + 2048, wh + 6144, w4, out, lv, N);
    } else if (ws_size >= encBytes + tableBytes + whBytes) {
        h2* table16 = (h2*)((char*)d_ws + encBytes);
        _Float16* wh = (_Float16*)((char*)d_ws + encBytes + tableBytes);
        const int total4 = 16 * T_SIZE / 4;              // 2,097,152
        const int convBlocks = (total4 + 10240 + 255) / 256;
        hipLaunchKernelGGL(convert_kernel, dim3(convBlocks), dim3(256), 0, stream,
                           (const float2*)table, table16, total4, w1, w2, w3, wh,
                           x, (unsigned short*)nullptr, N);
        hipLaunchKernelGGL(encode_kernel, dim3(ptBlocks, 10), dim3(256), 0, stream,
                           x, (const h2*)table16, enc2, lv, 5, N);
        hipLaunchKernelGGL((fused_kernel<_Float16, true, false>), dim3(ptBlocks), dim3(256),
                           0, stream, x, (const float4*)nullptr, (const h2*)table16,
                           (const h2*)enc2, wh, wh + 2048, wh + 6144, w4, out, lv, N);
    } else {
        hipLaunchKernelGGL(encode_kernel_f32, dim3(ptBlocks, 16), dim3(256), 0, stream,
                           x, (const float2*)table, enc2, lv, N);
        hipLaunchKernelGGL((fused_kernel<float, false, false>), dim3(ptBlocks), dim3(256),
                           0, stream, x, (const float4*)nullptr, (const h2*)nullptr,
                           (const h2*)enc2, w1, w2, w3, w4, out, lv, N);
    }
}

// Round 4
// 475.220 us; speedup vs baseline: 1.0127x; 1.0127x over previous
//
#include <hip/hip_runtime.h>
#include <cmath>

#define T_SIZE (1u << 19)
#define CB 512                    // coarse Morton bins (3 bits/dim)
#define NBLK 512                  // sort blocks (2048 pts each)
#define RCAP 3584                 // refine LDS point capacity (expected 2048/bin)

typedef _Float16 h8 __attribute__((ext_vector_type(8)));
typedef _Float16 h4 __attribute__((ext_vector_type(4)));
typedef _Float16 h2 __attribute__((ext_vector_type(2)));
typedef float f4 __attribute__((ext_vector_type(4)));

struct Levels {
    float scale[16];
    int   res[16];
    unsigned dense_mask;
};

// softplus(10z)/10, branch-free
__device__ __forceinline__ float softplus10(float z) {
    float e = __builtin_amdgcn_exp2f(fminf(z * 14.426950408889634f, 126.0f)); // e^{10z}
    return __builtin_amdgcn_logf(1.0f + e) * 0.069314718055994531f;
}

// ---------------- Morton helpers --------------------------------------------
__device__ __forceinline__ unsigned spread3(unsigned v) {
    v &= 1023u;
    v = (v | (v << 16)) & 0x030000FFu;
    v = (v | (v << 8))  & 0x0300F00Fu;
    v = (v | (v << 4))  & 0x030C30C3u;
    v = (v | (v << 2))  & 0x09249249u;
    return v;
}

__device__ __forceinline__ unsigned morton_key(float px, float py, float pz) {
    unsigned qx = (unsigned)fminf(fmaxf(px, 0.f) * 32.f, 31.f);
    unsigned qy = (unsigned)fminf(fmaxf(py, 0.f) * 32.f, 31.f);
    unsigned qz = (unsigned)fminf(fmaxf(pz, 0.f) * 32.f, 31.f);
    return (spread3(qx) << 2) | (spread3(qy) << 1) | spread3(qz);  // 15 bits
}

// -------- Kernel 0: table f32->f16 + weights f32->f16 + FUSED hist ----------
__global__ __launch_bounds__(256) void convert_kernel(
    const float2* __restrict__ t, h2* __restrict__ o, int total4,
    const float* __restrict__ w1, const float* __restrict__ w2,
    const float* __restrict__ w3, _Float16* __restrict__ wh,
    const float* __restrict__ xs, unsigned short* __restrict__ M, int N)
{
    const int histStart = (total4 + 10240 + 255) >> 8;
    if ((int)blockIdx.x >= histStart) {
        __shared__ unsigned h[CB];
        const int blk = blockIdx.x - histStart;
        for (int t2 = threadIdx.x; t2 < CB; t2 += 256) h[t2] = 0u;
        __syncthreads();
        const int s = blk * 2048;
#pragma unroll
        for (int j = 0; j < 8; ++j) {
            int i = s + threadIdx.x + j * 256;
            unsigned k = morton_key(xs[3 * i], xs[3 * i + 1], xs[3 * i + 2]) >> 6;
            atomicAdd(&h[k], 1u);              // LDS atomic
        }
        __syncthreads();
        for (int t2 = threadIdx.x; t2 < CB; t2 += 256)
            M[t2 * NBLK + blk] = (unsigned short)h[t2];
        return;
    }
    int i = blockIdx.x * 256 + threadIdx.x;
    if (i < total4) {
        const float2* src = t + (size_t)i * 4;
        h8 r;
#pragma unroll
        for (int j = 0; j < 4; ++j) {
            float2 v = src[j];
            r[2 * j]     = (_Float16)v.x;
            r[2 * j + 1] = (_Float16)v.y;
        }
        *(h8*)(o + (size_t)i * 4) = r;
    } else {
        int k = i - total4;                    // 40 extra blocks: 10240 weights
        if (k < 10240) {
            float v = (k < 2048) ? w1[k] : (k < 6144) ? w2[k - 2048] : w3[k - 6144];
            wh[k] = (_Float16)v;
        }
    }
}

// one block: exclusive scan of CB*NBLK = 262144 ushort counters (vectorized)
__global__ __launch_bounds__(1024) void scan_kernel(
    const unsigned short* __restrict__ M, unsigned* __restrict__ Ms)
{
    __shared__ unsigned tmp[1024];
    const int t = threadIdx.x;
    const int PERS = (CB * NBLK) / 1024;       // 256 ushorts/thread
    const uint4* mv = (const uint4*)(M + t * PERS);   // 32 x uint4 (8 ushorts)
    unsigned s = 0;
#pragma unroll 4
    for (int j = 0; j < PERS / 8; ++j) {
        uint4 v = mv[j];
        s += (v.x & 0xFFFFu) + (v.x >> 16) + (v.y & 0xFFFFu) + (v.y >> 16)
           + (v.z & 0xFFFFu) + (v.z >> 16) + (v.w & 0xFFFFu) + (v.w >> 16);
    }
    tmp[t] = s;
    __syncthreads();
    for (int d = 1; d < 1024; d <<= 1) {
        unsigned v = (t >= d) ? tmp[t - d] : 0u;
        __syncthreads();
        tmp[t] += v;
        __syncthreads();
    }
    unsigned run = (t > 0) ? tmp[t - 1] : 0u;
    for (int j = 0; j < PERS; ++j) {
        unsigned v = M[t * PERS + j];
        Ms[t * PERS + j] = run;
        run += v;
    }
}

// coarse scatter with LOCAL LDS SORT: stores become monotone 64B runs
__global__ __launch_bounds__(256) void cscatter_kernel(
    const float* __restrict__ xs, const unsigned* __restrict__ Ms,
    float4* __restrict__ sx4, int N)
{
    __shared__ float4  pts[2048];              // 32KB sorted points
    __shared__ unsigned gp[2048];              // 8KB global positions
    __shared__ unsigned lh[CB];                // hist, then cursors
    __shared__ unsigned lbase[CB];
    __shared__ unsigned tmp[256];
    const int tid = threadIdx.x;
    const int blk = blockIdx.x;
    for (int t2 = tid; t2 < CB; t2 += 256) lh[t2] = 0u;
    __syncthreads();
    const int s = blk * 2048;
    float4  myp[8];
    unsigned myk[8];
#pragma unroll
    for (int j = 0; j < 8; ++j) {
        int i = s + tid + j * 256;
        float px = xs[3 * i], py = xs[3 * i + 1], pz = xs[3 * i + 2];
        myp[j] = make_float4(px, py, pz, __uint_as_float((unsigned)i));
        myk[j] = morton_key(px, py, pz) >> 6;
        atomicAdd(&lh[myk[j]], 1u);
    }
    __syncthreads();
    unsigned a0 = lh[2 * tid], a1 = lh[2 * tid + 1];
    tmp[tid] = a0 + a1;
    __syncthreads();
    for (int d = 1; d < 256; d <<= 1) {
        unsigned v = (tid >= d) ? tmp[tid - d] : 0u;
        __syncthreads();
        tmp[tid] += v;
        __syncthreads();
    }
    unsigned eb = (tid > 0) ? tmp[tid - 1] : 0u;
    lbase[2 * tid] = eb;
    lbase[2 * tid + 1] = eb + a0;
    __syncthreads();
    lh[2 * tid] = 0u; lh[2 * tid + 1] = 0u;    // reset as cursors
    __syncthreads();
#pragma unroll
    for (int j = 0; j < 8; ++j) {
        unsigned k = myk[j];
        unsigned r = atomicAdd(&lh[k], 1u);
        unsigned slot = lbase[k] + r;
        pts[slot] = myp[j];
        gp[slot] = Ms[k * NBLK + blk] + r;
    }
    __syncthreads();
    for (int j = tid; j < 2048; j += 256)
        sx4[gp[j]] = pts[j];                   // monotone, run-coalesced
}

// one block per coarse bin: in-place sort by low 6 Morton bits
__global__ __launch_bounds__(256) void refine_kernel(
    float4* __restrict__ sx4, const unsigned* __restrict__ Ms, int N)
{
    __shared__ float4 pts[RCAP];
    __shared__ unsigned h[64], base[64];
    const int b = blockIdx.x;
    const unsigned s = Ms[b * NBLK];
    const unsigned e = (b == CB - 1) ? (unsigned)N : Ms[(b + 1) * NBLK];
    const unsigned cnt = e - s;
    if (cnt > RCAP) return;                    // block-uniform: safe
    if (threadIdx.x < 64) h[threadIdx.x] = 0u;
    __syncthreads();
    for (unsigned i = threadIdx.x; i < cnt; i += 256) {
        float4 q = sx4[s + i];
        pts[i] = q;
        unsigned k = morton_key(q.x, q.y, q.z) & 63u;
        atomicAdd(&h[k], 1u);
    }
    __syncthreads();
    if (threadIdx.x == 0) {
        unsigned a = 0;
        for (int j = 0; j < 64; ++j) { base[j] = a; a += h[j]; }
    }
    __syncthreads();
    if (threadIdx.x < 64) h[threadIdx.x] = 0u;
    __syncthreads();
    for (unsigned i = threadIdx.x; i < cnt; i += 256) {
        float4 q = pts[i];
        unsigned k = morton_key(q.x, q.y, q.z) & 63u;
        unsigned r = base[k] + atomicAdd(&h[k], 1u);
        sx4[s + r] = q;
    }
}

// Two-corner gather, 16B-group version (RESTORED: dense levels always have
// x-adjacent corners -> group covers both for ~3/4 of lanes, 1.25 loads/pair).
__device__ __forceinline__ void gather_pair(
    const h2* __restrict__ tl, unsigned i0, unsigned i1,
    float2& v0, float2& v1)
{
    unsigned g = i0 & ~3u;
    union { h8 v; uint4 u; } cv;
    cv.v = *(const h8*)(tl + g);
    unsigned p0 = i0 & 3u;
    unsigned a01 = (p0 & 1u) ? cv.u.y : cv.u.x;
    unsigned a23 = (p0 & 1u) ? cv.u.w : cv.u.z;
    unsigned e0  = (p0 & 2u) ? a23 : a01;
    unsigned e1;
    if ((i1 & ~3u) == g) {
        unsigned p1 = i1 & 3u;
        unsigned b01 = (p1 & 1u) ? cv.u.y : cv.u.x;
        unsigned b23 = (p1 & 1u) ? cv.u.w : cv.u.z;
        e1 = (p1 & 2u) ? b23 : b01;
    } else {
        e1 = *(const unsigned*)(tl + i1);
    }
    h2 c0 = __builtin_bit_cast(h2, e0);
    h2 c1 = __builtin_bit_cast(h2, e1);
    v0 = make_float2((float)c0[0], (float)c0[1]);
    v1 = make_float2((float)c1[0], (float)c1[1]);
}

// full per-(point,level) encode -> packed h2 feature pair
__device__ __forceinline__ h2 encode_point(
    float px, float py, float pz, float s, int res, bool dense,
    const h2* __restrict__ tl)
{
    float fx = px * s + 0.5f, fy = py * s + 0.5f, fz = pz * s + 0.5f;
    float gx = floorf(fx), gy = floorf(fy), gz = floorf(fz);
    float wx = fx - gx, wy = fy - gy, wz = fz - gz;
    int cx = (int)gx, cy = (int)gy, cz = (int)gz;

    float2 vx0[4], vx1[4];             // combo j: y=(j>>1), z=(j&1)
    if (dense) {
        int r1 = res - 1;
        int x0 = min(cx, r1), x1 = min(cx + 1, r1);
        int y0 = min(cy, r1), y1 = min(cy + 1, r1);
        int z0 = min(cz, r1), z1 = min(cz + 1, r1);
        int rr = res * res;
        int bases[4] = {y0 * res + z0 * rr, y0 * res + z1 * rr,
                        y1 * res + z0 * rr, y1 * res + z1 * rr};
#pragma unroll
        for (int j = 0; j < 4; ++j)
            gather_pair(tl, (unsigned)(x0 + bases[j]), (unsigned)(x1 + bases[j]),
                        vx0[j], vx1[j]);
    } else {
        unsigned hy0 = (unsigned)cy * 2654435761u, hy1 = (unsigned)(cy + 1) * 2654435761u;
        unsigned hz0 = (unsigned)cz * 805459861u,  hz1 = (unsigned)(cz + 1) * 805459861u;
        unsigned Y[4] = {hy0 ^ hz0, hy0 ^ hz1, hy1 ^ hz0, hy1 ^ hz1};
        const unsigned M = T_SIZE - 1;
#pragma unroll
        for (int j = 0; j < 4; ++j)
            gather_pair(tl, ((unsigned)cx ^ Y[j]) & M,
                        ((unsigned)(cx + 1) ^ Y[j]) & M, vx0[j], vx1[j]);
    }

    float wx0 = 1.f - wx, wy0 = 1.f - wy, wz0 = 1.f - wz;
    float wyz[4] = {wy0 * wz0, wy0 * wz, wy * wz0, wy * wz};
    float f0 = 0.f, f1 = 0.f;
#pragma unroll
    for (int j = 0; j < 4; ++j) {
        float w0 = wx0 * wyz[j], w1 = wx * wyz[j];
        f0 += w0 * vx0[j].x + w1 * vx1[j].x;
        f1 += w0 * vx0[j].y + w1 * vx1[j].y;
    }
    h2 r; r[0] = (_Float16)f0; r[1] = (_Float16)f1;
    return r;
}

// ---- split encode: prep (indices) / batched loads / finish (weights) -------
// Enables 2 points/thread with ALL gather loads issued before any use:
// doubles in-flight lines per wave (encode was latency-bound: 0.23 lines/cy/CU
// measured vs ~1 available; VALUBusy 22%, VGPR 16 -> huge MLP headroom).
struct PLCtx {
    unsigned g[4], p0[4], i1[4], sg[4];
    float wx, wy, wz;
};

__device__ __forceinline__ void prep_point(
    float px, float py, float pz, float s, int res, bool dense, PLCtx& c)
{
    float fx = px * s + 0.5f, fy = py * s + 0.5f, fz = pz * s + 0.5f;
    float gx = floorf(fx), gy = floorf(fy), gz = floorf(fz);
    c.wx = fx - gx; c.wy = fy - gy; c.wz = fz - gz;
    int cx = (int)gx, cy = (int)gy, cz = (int)gz;
    unsigned i0[4], i1[4];
    if (dense) {
        int r1 = res - 1;
        int x0 = min(cx, r1), x1 = min(cx + 1, r1);
        int y0 = min(cy, r1), y1 = min(cy + 1, r1);
        int z0 = min(cz, r1), z1 = min(cz + 1, r1);
        int rr = res * res;
        int bases[4] = {y0 * res + z0 * rr, y0 * res + z1 * rr,
                        y1 * res + z0 * rr, y1 * res + z1 * rr};
#pragma unroll
        for (int j = 0; j < 4; ++j) {
            i0[j] = (unsigned)(x0 + bases[j]);
            i1[j] = (unsigned)(x1 + bases[j]);
        }
    } else {
        unsigned hy0 = (unsigned)cy * 2654435761u, hy1 = (unsigned)(cy + 1) * 2654435761u;
        unsigned hz0 = (unsigned)cz * 805459861u,  hz1 = (unsigned)(cz + 1) * 805459861u;
        unsigned Y[4] = {hy0 ^ hz0, hy0 ^ hz1, hy1 ^ hz0, hy1 ^ hz1};
        const unsigned M = T_SIZE - 1;
#pragma unroll
        for (int j = 0; j < 4; ++j) {
            i0[j] = ((unsigned)cx ^ Y[j]) & M;
            i1[j] = ((unsigned)(cx + 1) ^ Y[j]) & M;
        }
    }
#pragma unroll
    for (int j = 0; j < 4; ++j) {
        c.g[j]  = i0[j] & ~3u;
        c.p0[j] = i0[j] & 3u;
        c.i1[j] = i1[j];
        c.sg[j] = ((i1[j] & ~3u) == c.g[j]) ? 1u : 0u;
    }
}

__device__ __forceinline__ h2 finish_point(
    const uint4 cv[4], const unsigned e1x[4], const PLCtx& c)
{
    float wx0 = 1.f - c.wx, wy0 = 1.f - c.wy, wz0 = 1.f - c.wz;
    float wyz[4] = {wy0 * wz0, wy0 * c.wz, c.wy * wz0, c.wy * c.wz};
    float f0 = 0.f, f1 = 0.f;
#pragma unroll
    for (int j = 0; j < 4; ++j) {
        unsigned p0 = c.p0[j];
        unsigned a01 = (p0 & 1u) ? cv[j].y : cv[j].x;
        unsigned a23 = (p0 & 1u) ? cv[j].w : cv[j].z;
        unsigned e0  = (p0 & 2u) ? a23 : a01;
        unsigned p1 = c.i1[j] & 3u;
        unsigned b01 = (p1 & 1u) ? cv[j].y : cv[j].x;
        unsigned b23 = (p1 & 1u) ? cv[j].w : cv[j].z;
        unsigned eg  = (p1 & 2u) ? b23 : b01;
        unsigned e1  = c.sg[j] ? eg : e1x[j];
        h2 c0 = __builtin_bit_cast(h2, e0);
        h2 c1 = __builtin_bit_cast(h2, e1);
        float w0 = wx0 * wyz[j], w1 = c.wx * wyz[j];
        f0 += w0 * (float)c0[0] + w1 * (float)c1[0];
        f1 += w0 * (float)c0[1] + w1 * (float)c1[1];
    }
    h2 r; r[0] = (_Float16)f0; r[1] = (_Float16)f1;
    return r;
}

// ---------------- Kernel A (phase 1): hash levels lbase.. -> enc2 [16][N] ----
__global__ __launch_bounds__(256) void encode_kernel(
    const float* __restrict__ xs, const h2* __restrict__ table,
    h2* __restrict__ enc2, Levels lv, int lbase, int N)
{
    __shared__ float sx[768];
    const int i0 = blockIdx.x * 256;
    for (int t = threadIdx.x; t < 768; t += 256) sx[t] = xs[(size_t)i0 * 3 + t];
    __syncthreads();

    const int l = lbase + blockIdx.y;
    const int i = i0 + threadIdx.x;
    if (i >= N) return;
    h2 r = encode_point(sx[threadIdx.x * 3], sx[threadIdx.x * 3 + 1],
                        sx[threadIdx.x * 3 + 2], lv.scale[l], lv.res[l],
                        (lv.dense_mask >> l) & 1u, table + (size_t)l * T_SIZE);
    enc2[(size_t)l * N + i] = r;       // coalesced 4B store
}

// sorted variant, 2 POINTS/THREAD: prep both, issue ALL gathers, then finish.
__global__ __launch_bounds__(256) void encode_kernel_sorted(
    const float4* __restrict__ xs4, const h2* __restrict__ table,
    h2* __restrict__ enc2, Levels lv, int lbase, int N)
{
    const int i = blockIdx.x * 512 + threadIdx.x;
    const int l = lbase + blockIdx.y;
    const h2* tl = table + (size_t)l * T_SIZE;
    const float s = lv.scale[l];
    const int res = lv.res[l];
    const bool dense = (lv.dense_mask >> l) & 1u;

    float4 qa = xs4[i];
    float4 qb = xs4[i + 256];
    PLCtx ca, cb;
    prep_point(qa.x, qa.y, qa.z, s, res, dense, ca);
    prep_point(qb.x, qb.y, qb.z, s, res, dense, cb);

    uint4 cva[4], cvb[4];
    unsigned ea[4], eb[4];
#pragma unroll
    for (int j = 0; j < 4; ++j) cva[j] = *(const uint4*)(tl + ca.g[j]);
#pragma unroll
    for (int j = 0; j < 4; ++j) cvb[j] = *(const uint4*)(tl + cb.g[j]);
#pragma unroll
    for (int j = 0; j < 4; ++j)
        ea[j] = ca.sg[j] ? 0u : *(const unsigned*)(tl + ca.i1[j]);
#pragma unroll
    for (int j = 0; j < 4; ++j)
        eb[j] = cb.sg[j] ? 0u : *(const unsigned*)(tl + cb.i1[j]);

    enc2[(size_t)l * N + i]       = finish_point(cva, ea, ca);
    enc2[(size_t)l * N + i + 256] = finish_point(cvb, eb, cb);
}

// generic 8-half fragment load (f16 direct dwordx4, or f32 + convert)
template <typename WT>
__device__ __forceinline__ h8 load_frag8(const WT* p) {
    if constexpr (sizeof(WT) == 2) {
        return *(const h8*)p;
    } else {
        h8 r;
#pragma unroll
        for (int j = 0; j < 8; ++j) r[j] = (_Float16)p[j];
        return r;
    }
}

// ------------- Kernel B (fused): encode levels {0-4,15} locally + MLP -------
template <typename WT, bool LOCAL, bool SORTED>
__global__ __launch_bounds__(256, 3) void fused_kernel(
    const float* __restrict__ xs, const float4* __restrict__ xs4,
    const h2* __restrict__ table16, const h2* __restrict__ enc2,
    const WT* __restrict__ w1, const WT* __restrict__ w2,
    const WT* __restrict__ w3, const float* __restrict__ w4,
    float* __restrict__ out, Levels lv, int N)
{
    constexpr int AR = 72;                          // 144B act rows, 16B-aligned
    __shared__ __align__(16) char smem[4 * 9216];   // per-wave: sEnc ∪ sAct
    __shared__ float sx[768];

    const int tid  = threadIdx.x;
    const int wave = tid >> 6;
    const int lane = tid & 63;
    const int lrow = lane & 15;
    const int quad = lane >> 4;
    const int base = blockIdx.x * 256;
    char* wmem = smem + wave * 9216;
    const f4 zero = {0.f, 0.f, 0.f, 0.f};

    float px, py, pz;
    unsigned oi = 0;
    if constexpr (SORTED) {
        float4 q = xs4[base + tid];
        px = q.x; py = q.y; pz = q.z;
        oi = __float_as_uint(q.w);
    } else {
        for (int t = tid; t < 768; t += 256) sx[t] = xs[(size_t)base * 3 + t];
        __syncthreads();
        px = sx[tid * 3]; py = sx[tid * 3 + 1]; pz = sx[tid * 3 + 2];
    }
    const int p = tid & 63;                         // local point in wave region

    // sEnc layout (transposed): byte = (l>>2)*1024 + p*16 + (l&3)*4
    if (LOCAL) {
#pragma unroll
        for (int l = 5; l < 15; ++l) {              // 10 coalesced 4B global loads
            h2 v = enc2[(size_t)l * N + base + tid];
            *(h2*)(wmem + ((l >> 2) << 10) + (p << 4) + ((l & 3) << 2)) = v;
        }
        const int LMAP[6] = {0, 1, 2, 3, 4, 15};
#pragma unroll 2
        for (int s6 = 0; s6 < 6; ++s6) {
            const int l = LMAP[s6];
            h2 v = encode_point(px, py, pz, lv.scale[l], lv.res[l],
                                (lv.dense_mask >> l) & 1u,
                                table16 + (size_t)l * T_SIZE);
            *(h2*)(wmem + ((l >> 2) << 10) + (p << 4) + ((l & 3) << 2)) = v;
        }
    } else {
#pragma unroll
        for (int l = 0; l < 16; ++l) {
            h2 v = enc2[(size_t)l * N + base + tid];
            *(h2*)(wmem + ((l >> 2) << 10) + (p << 4) + ((l & 3) << 2)) = v;
        }
    }

    asm volatile("" ::: "memory");   // keep weight loads after encode (pressure)

    // weight A-frags (L2-hot) + packed w4
    h8 aW1[4];
#pragma unroll
    for (int tm = 0; tm < 4; ++tm)
        aW1[tm] = load_frag8(w1 + (tm * 16 + lrow) * 32 + quad * 8);
    h8 aW2[4][2], aW3[4][2];
#pragma unroll
    for (int tm = 0; tm < 4; ++tm)
#pragma unroll
        for (int km = 0; km < 2; ++km) {
            aW2[tm][km] = load_frag8(w2 + (tm * 16 + lrow) * 64 + km * 32 + quad * 8);
            aW3[tm][km] = load_frag8(w3 + (tm * 16 + lrow) * 64 + km * 32 + quad * 8);
        }
    h4 w4q[4];
#pragma unroll
    for (int tm = 0; tm < 4; ++tm)
#pragma unroll
        for (int r = 0; r < 4; ++r) w4q[tm][r] = (_Float16)w4[tm * 16 + quad * 4 + r];

    // pre-read ALL layer-1 B-frags BEFORE sAct overwrites the sEnc region.
    h8 bin[4];
#pragma unroll
    for (int t = 0; t < 4; ++t)
        bin[t] = *(const h8*)(wmem + (quad << 10) + ((t * 16 + lrow) << 4));

    _Float16* wAct = (_Float16*)wmem;               // local rows 0..63, stride AR

    // ---- Layer 1: D1 = W1 · enc^T ----
#pragma unroll
    for (int t = 0; t < 4; ++t) {
        const int arow = (t * 16 + lrow) * AR;
#pragma unroll
        for (int tm = 0; tm < 4; ++tm) {
            f4 acc = __builtin_amdgcn_mfma_f32_16x16x32_f16(aW1[tm], bin[t], zero, 0, 0, 0);
            h4 pk;
#pragma unroll
            for (int r = 0; r < 4; ++r) pk[r] = (_Float16)softplus10(acc[r]);
            *(h4*)&wAct[arow + tm * 16 + quad * 4] = pk;
        }
    }

    // ---- Layer 2: D2 = W2 · act1^T ----
#pragma unroll
    for (int t = 0; t < 4; ++t) {
        const int arow = (t * 16 + lrow) * AR;
        h8 b0 = *(const h8*)&wAct[arow + quad * 8];
        h8 b1 = *(const h8*)&wAct[arow + 32 + quad * 8];
        f4 accs[4];
#pragma unroll
        for (int tm = 0; tm < 4; ++tm) {
            f4 acc = __builtin_amdgcn_mfma_f32_16x16x32_f16(aW2[tm][0], b0, zero, 0, 0, 0);
            acc     = __builtin_amdgcn_mfma_f32_16x16x32_f16(aW2[tm][1], b1, acc,  0, 0, 0);
            accs[tm] = acc;
        }
#pragma unroll
        for (int tm = 0; tm < 4; ++tm) {
            h4 pk;
#pragma unroll
            for (int r = 0; r < 4; ++r) pk[r] = (_Float16)softplus10(accs[tm][r]);
            *(h4*)&wAct[arow + tm * 16 + quad * 4] = pk;
        }
    }

    // ---- Layer 3+4 fused: sdf = w4 · softplus(W3 · act2^T) ----
#pragma unroll
    for (int t = 0; t < 4; ++t) {
        const int arow = (t * 16 + lrow) * AR;
        h8 b0 = *(const h8*)&wAct[arow + quad * 8];
        h8 b1 = *(const h8*)&wAct[arow + 32 + quad * 8];
        float sum = 0.f;
#pragma unroll
        for (int tm = 0; tm < 4; ++tm) {
            f4 acc = __builtin_amdgcn_mfma_f32_16x16x32_f16(aW3[tm][0], b0, zero, 0, 0, 0);
            acc     = __builtin_amdgcn_mfma_f32_16x16x32_f16(aW3[tm][1], b1, acc,  0, 0, 0);
#pragma unroll
            for (int r = 0; r < 4; ++r)
                sum += (float)w4q[tm][r] * softplus10(acc[r]);
        }
        sum += __shfl_xor(sum, 16, 64);
        sum += __shfl_xor(sum, 32, 64);
        if constexpr (SORTED) {
            unsigned t_oi = __shfl(oi, t * 16 + lrow, 64);
            if (quad == 0) out[t_oi] = sum;
        } else {
            if (quad == 0)
                out[base + wave * 64 + t * 16 + lrow] = sum;
        }
    }
}

// Fallback encode (f32 table, all 16 levels) if workspace too small
__global__ __launch_bounds__(256) void encode_kernel_f32(
    const float* __restrict__ xs, const float2* __restrict__ table,
    h2* __restrict__ enc2, Levels lv, int N)
{
    const int i = blockIdx.x * 256 + threadIdx.x;
    const int l = blockIdx.y;
    if (i >= N) return;
    float px = xs[3 * i], py = xs[3 * i + 1], pz = xs[3 * i + 2];
    float s = lv.scale[l];
    int res = lv.res[l];
    float fx = px * s + 0.5f, fy = py * s + 0.5f, fz = pz * s + 0.5f;
    float gx = floorf(fx), gy = floorf(fy), gz = floorf(fz);
    float wx = fx - gx, wy = fy - gy, wz = fz - gz;
    int cx = (int)gx, cy = (int)gy, cz = (int)gz;
    unsigned idx[8];
    if ((lv.dense_mask >> l) & 1u) {
        int r1 = res - 1;
        int x0 = min(cx, r1), x1 = min(cx + 1, r1);
        int y0 = min(cy, r1), y1 = min(cy + 1, r1);
        int z0 = min(cz, r1), z1 = min(cz + 1, r1);
        int rr = res * res;
        idx[0] = x0 + y0 * res + z0 * rr; idx[1] = x0 + y0 * res + z1 * rr;
        idx[2] = x0 + y1 * res + z0 * rr; idx[3] = x0 + y1 * res + z1 * rr;
        idx[4] = x1 + y0 * res + z0 * rr; idx[5] = x1 + y0 * res + z1 * rr;
        idx[6] = x1 + y1 * res + z0 * rr; idx[7] = x1 + y1 * res + z1 * rr;
    } else {
        unsigned hx0 = (unsigned)cx, hx1 = (unsigned)(cx + 1);
        unsigned hy0 = (unsigned)cy * 2654435761u, hy1 = (unsigned)(cy + 1) * 2654435761u;
        unsigned hz0 = (unsigned)cz * 805459861u,  hz1 = (unsigned)(cz + 1) * 805459861u;
        idx[0] = (hx0^hy0^hz0) & (T_SIZE-1); idx[1] = (hx0^hy0^hz1) & (T_SIZE-1);
        idx[2] = (hx0^hy1^hz0) & (T_SIZE-1); idx[3] = (hx0^hy1^hz1) & (T_SIZE-1);
        idx[4] = (hx1^hy0^hz0) & (T_SIZE-1); idx[5] = (hx1^hy0^hz1) & (T_SIZE-1);
        idx[6] = (hx1^hy1^hz0) & (T_SIZE-1); idx[7] = (hx1^hy1^hz1) & (T_SIZE-1);
    }
    const float2* tl = table + (size_t)l * T_SIZE;
    float wx0 = 1.f - wx, wy0 = 1.f - wy, wz0 = 1.f - wz;
    float wcs[8] = {wx0*wy0*wz0, wx0*wy0*wz, wx0*wy*wz0, wx0*wy*wz,
                    wx*wy0*wz0,  wx*wy0*wz,  wx*wy*wz0,  wx*wy*wz};
    float f0 = 0.f, f1 = 0.f;
#pragma unroll
    for (int c = 0; c < 8; ++c) {
        float2 v = tl[idx[c]];
        f0 += wcs[c] * v.x; f1 += wcs[c] * v.y;
    }
    h2 r; r[0] = (_Float16)f0; r[1] = (_Float16)f1;
    enc2[(size_t)l * N + i] = r;
}

extern "C" void kernel_launch(void* const* d_in, const int* in_sizes, int n_in,
                              void* d_out, int out_size, void* d_ws, size_t ws_size,
                              hipStream_t stream) {
    const float* x     = (const float*)d_in[0];
    const float* table = (const float*)d_in[1];
    const float* w1    = (const float*)d_in[2];
    const float* w2    = (const float*)d_in[3];
    const float* w3    = (const float*)d_in[4];
    const float* w4    = (const float*)d_in[5];
    float* out = (float*)d_out;
    const int N = in_sizes[0] / 3;                 // 1<<20

    Levels lv;
    lv.dense_mask = 0;
    const double pls = exp2(log2(2048.0 / 16.0) / 15.0);
    const double lg  = log2(pls);
    for (int l = 0; l < 16; ++l) {
        double sc = exp2((double)l * lg) * 16.0 - 1.0;
        int res = (int)ceil(sc) + 1;
        lv.scale[l] = (float)sc;
        lv.res[l]   = res;
        if ((long long)res * res * res <= (long long)T_SIZE) lv.dense_mask |= (1u << l);
    }

    const size_t encBytes   = (size_t)16 * N * 4;        // 64 MB ([16][N] h2)
    const size_t tableBytes = (size_t)16 * T_SIZE * 4;   // 33.5 MB f16 table
    const size_t whBytes    = 32768;                     // 10240 f16 weights
    const size_t sx4Bytes   = (size_t)N * 16;            // 16 MB sorted float4
    h2* enc2 = (h2*)d_ws;

    const int ptBlocks = (N + 255) / 256;                // 4096

    if (ws_size >= encBytes + tableBytes + whBytes + sx4Bytes
        && N == NBLK * 2048) {
        h2* table16    = (h2*)((char*)d_ws + encBytes);
        _Float16* wh   = (_Float16*)((char*)d_ws + encBytes + tableBytes);
        float4* sx4    = (float4*)((char*)d_ws + encBytes + tableBytes + whBytes);
        // M/Ms live inside enc2's level-0..4 region (never written here:
        // fused computes levels 0-4 & 15 locally; encode writes only 5..14).
        unsigned short* M = (unsigned short*)d_ws;                       // 512KB
        unsigned* Ms      = (unsigned*)((char*)d_ws + 1024 * 1024);      // 1MB

        const int total4 = 16 * T_SIZE / 4;              // 2,097,152
        const int convBlocks = (total4 + 10240 + 255) / 256;
        hipLaunchKernelGGL(convert_kernel, dim3(convBlocks + NBLK), dim3(256), 0,
                           stream, (const float2*)table, table16, total4,
                           w1, w2, w3, wh, x, M, N);
        hipLaunchKernelGGL(scan_kernel, dim3(1), dim3(1024), 0, stream, M, Ms);
        hipLaunchKernelGGL(cscatter_kernel, dim3(NBLK), dim3(256), 0, stream,
                           x, Ms, sx4, N);
        hipLaunchKernelGGL(refine_kernel, dim3(CB), dim3(256), 0, stream,
                           sx4, Ms, N);

        // phase 1: hash levels 5..14, sorted, 2 pts/thread
        hipLaunchKernelGGL(encode_kernel_sorted, dim3(ptBlocks / 2, 10), dim3(256),
                           0, stream, (const float4*)sx4, (const h2*)table16,
                           enc2, lv, 5, N);
        // phase 2: fused local-encode {0-4,15} + MLP, scatter to out[orig]
        hipLaunchKernelGGL((fused_kernel<_Float16, true, true>), dim3(ptBlocks), dim3(256),
                           0, stream, x, (const float4*)sx4, (const h2*)table16,
                           (const h2*)enc2, wh, wh + 2048, wh + 6144, w4, out, lv, N);
    } else if (ws_size >= encBytes + tableBytes + whBytes) {
        h2* table16 = (h2*)((char*)d_ws + encBytes);
        _Float16* wh = (_Float16*)((char*)d_ws + encBytes + tableBytes);
        const int total4 = 16 * T_SIZE / 4;              // 2,097,152
        const int convBlocks = (total4 + 10240 + 255) / 256;
        hipLaunchKernelGGL(convert_kernel, dim3(convBlocks), dim3(256), 0, stream,
                           (const float2*)table, table16, total4, w1, w2, w3, wh,
                           x, (unsigned short*)nullptr, N);
        hipLaunchKernelGGL(encode_kernel, dim3(ptBlocks, 10), dim3(256), 0, stream,
                           x, (const h2*)table16, enc2, lv, 5, N);
        hipLaunchKernelGGL((fused_kernel<_Float16, true, false>), dim3(ptBlocks), dim3(256),
                           0, stream, x, (const float4*)nullptr, (const h2*)table16,
                           (const h2*)enc2, wh, wh + 2048, wh + 6144, w4, out, lv, N);
    } else {
        hipLaunchKernelGGL(encode_kernel_f32, dim3(ptBlocks, 16), dim3(256), 0, stream,
                           x, (const float2*)table, enc2, lv, N);
        hipLaunchKernelGGL((fused_kernel<float, false, false>), dim3(ptBlocks), dim3(256),
                           0, stream, x, (const float4*)nullptr, (const h2*)nullptr,
                           (const h2*)enc2, w1, w2, w3, w4, out, lv, N);
    }
}

// Round 5
// 450.586 us; speedup vs baseline: 1.0681x; 1.0547x over previous
//
#include <hip/hip_runtime.h>
#include <cmath>

#define T_SIZE (1u << 19)
#define CB 512                    // coarse Morton bins (3 bits/dim)
#define NBLK 128                  // hist/coarse-scatter blocks (8192 pts each)
#define RCAP 3584                 // refine LDS point capacity (expected 2048/bin)

typedef _Float16 h8 __attribute__((ext_vector_type(8)));
typedef _Float16 h4 __attribute__((ext_vector_type(4)));
typedef _Float16 h2 __attribute__((ext_vector_type(2)));
typedef float f4 __attribute__((ext_vector_type(4)));

struct Levels {
    float scale[16];
    int   res[16];
    unsigned dense_mask;
};

// softplus(10z)/10, branch-free
__device__ __forceinline__ float softplus10(float z) {
    float e = __builtin_amdgcn_exp2f(fminf(z * 14.426950408889634f, 126.0f)); // e^{10z}
    return __builtin_amdgcn_logf(1.0f + e) * 0.069314718055994531f;
}

// ---------------- Morton helpers --------------------------------------------
__device__ __forceinline__ unsigned spread3(unsigned v) {
    v &= 1023u;
    v = (v | (v << 16)) & 0x030000FFu;
    v = (v | (v << 8))  & 0x0300F00Fu;
    v = (v | (v << 4))  & 0x030C30C3u;
    v = (v | (v << 2))  & 0x09249249u;
    return v;
}

__device__ __forceinline__ unsigned morton_key(float px, float py, float pz) {
    unsigned qx = (unsigned)fminf(fmaxf(px, 0.f) * 32.f, 31.f);
    unsigned qy = (unsigned)fminf(fmaxf(py, 0.f) * 32.f, 31.f);
    unsigned qz = (unsigned)fminf(fmaxf(pz, 0.f) * 32.f, 31.f);
    return (spread3(qx) << 2) | (spread3(qy) << 1) | spread3(qz);  // 15 bits
}

// -------- Kernel 0: table f32->f16 + weights f32->f16 + FUSED hist ----------
// Extra NBLK blocks past the convert range do the coarse Morton histogram
// (independent work overlapping the BW-bound convert -> hist is ~free).
__global__ __launch_bounds__(256) void convert_kernel(
    const float2* __restrict__ t, h2* __restrict__ o, int total4,
    const float* __restrict__ w1, const float* __restrict__ w2,
    const float* __restrict__ w3, _Float16* __restrict__ wh,
    const float* __restrict__ xs, unsigned* __restrict__ M, int N)
{
    const int histStart = (total4 + 10240 + 255) >> 8;
    if ((int)blockIdx.x >= histStart) {
        __shared__ unsigned h[CB];
        const int blk = blockIdx.x - histStart;
        for (int t2 = threadIdx.x; t2 < CB; t2 += 256) h[t2] = 0u;
        __syncthreads();
        const int per = N / NBLK;                  // 8192
        const int s = blk * per;
        for (int i = s + threadIdx.x; i < s + per; i += 256) {
            unsigned k = morton_key(xs[3 * i], xs[3 * i + 1], xs[3 * i + 2]) >> 6;
            atomicAdd(&h[k], 1u);                  // LDS atomic
        }
        __syncthreads();
        for (int t2 = threadIdx.x; t2 < CB; t2 += 256)
            M[t2 * NBLK + blk] = h[t2];
        return;
    }
    int i = blockIdx.x * 256 + threadIdx.x;
    if (i < total4) {
        const float2* src = t + (size_t)i * 4;
        h8 r;
#pragma unroll
        for (int j = 0; j < 4; ++j) {
            float2 v = src[j];
            r[2 * j]     = (_Float16)v.x;
            r[2 * j + 1] = (_Float16)v.y;
        }
        *(h8*)(o + (size_t)i * 4) = r;
    } else {
        int k = i - total4;                    // 40 extra blocks: 10240 weights
        if (k < 10240) {
            float v = (k < 2048) ? w1[k] : (k < 6144) ? w2[k - 2048] : w3[k - 6144];
            wh[k] = (_Float16)v;
        }
    }
}

// one block: exclusive scan of CB*NBLK = 65536 counters (R2-proven shape)
__global__ __launch_bounds__(1024) void scan_kernel(
    const unsigned* __restrict__ M, unsigned* __restrict__ Ms)
{
    __shared__ unsigned tmp[1024];
    const int t = threadIdx.x;
    const int PER = (CB * NBLK) / 1024;        // 64
    unsigned s = 0;
    for (int j = 0; j < PER; ++j) s += M[t * PER + j];
    tmp[t] = s;
    __syncthreads();
    for (int d = 1; d < 1024; d <<= 1) {
        unsigned v = (t >= d) ? tmp[t - d] : 0u;
        __syncthreads();
        tmp[t] += v;
        __syncthreads();
    }
    unsigned run = (t > 0) ? tmp[t - 1] : 0u;
    for (int j = 0; j < PER; ++j) {
        unsigned v = M[t * PER + j];
        Ms[t * PER + j] = run;
        run += v;
    }
}

// coarse scatter: LDS cursors only, direct 16B stores (R2-proven version)
__global__ __launch_bounds__(256) void cscatter_kernel(
    const float* __restrict__ xs, const unsigned* __restrict__ Ms,
    float4* __restrict__ sx4, int N)
{
    __shared__ unsigned cur[CB];
    for (int t = threadIdx.x; t < CB; t += 256)
        cur[t] = Ms[t * NBLK + blockIdx.x];
    __syncthreads();
    const int per = N / NBLK;
    const int s = blockIdx.x * per;
    for (int i = s + threadIdx.x; i < s + per; i += 256) {
        float px = xs[3 * i], py = xs[3 * i + 1], pz = xs[3 * i + 2];
        unsigned k = morton_key(px, py, pz) >> 6;
        unsigned pos = atomicAdd(&cur[k], 1u); // LDS atomic -> absolute slot
        sx4[pos] = make_float4(px, py, pz, __uint_as_float((unsigned)i));
    }
}

// one block per coarse bin: in-place sort by low 6 Morton bits (R2-proven)
__global__ __launch_bounds__(256) void refine_kernel(
    float4* __restrict__ sx4, const unsigned* __restrict__ Ms, int N)
{
    __shared__ float4 pts[RCAP];
    __shared__ unsigned h[64], base[64];
    const int b = blockIdx.x;
    const unsigned s = Ms[b * NBLK];
    const unsigned e = (b == CB - 1) ? (unsigned)N : Ms[(b + 1) * NBLK];
    const unsigned cnt = e - s;
    if (cnt > RCAP) return;                    // block-uniform: safe
    if (threadIdx.x < 64) h[threadIdx.x] = 0u;
    __syncthreads();
    for (unsigned i = threadIdx.x; i < cnt; i += 256) {
        float4 q = sx4[s + i];
        pts[i] = q;
        unsigned k = morton_key(q.x, q.y, q.z) & 63u;
        atomicAdd(&h[k], 1u);
    }
    __syncthreads();
    if (threadIdx.x == 0) {
        unsigned a = 0;
        for (int j = 0; j < 64; ++j) { base[j] = a; a += h[j]; }
    }
    __syncthreads();
    if (threadIdx.x < 64) h[threadIdx.x] = 0u;
    __syncthreads();
    for (unsigned i = threadIdx.x; i < cnt; i += 256) {
        float4 q = pts[i];
        unsigned k = morton_key(q.x, q.y, q.z) & 63u;
        unsigned r = base[k] + atomicAdd(&h[k], 1u);
        sx4[s + r] = q;
    }
}

// Two-corner gather, 16B-group version (proven best: dense levels always have
// x-adjacent corners -> group covers both for ~3/4 of lanes).
__device__ __forceinline__ void gather_pair(
    const h2* __restrict__ tl, unsigned i0, unsigned i1,
    float2& v0, float2& v1)
{
    unsigned g = i0 & ~3u;
    union { h8 v; uint4 u; } cv;
    cv.v = *(const h8*)(tl + g);
    unsigned p0 = i0 & 3u;
    unsigned a01 = (p0 & 1u) ? cv.u.y : cv.u.x;
    unsigned a23 = (p0 & 1u) ? cv.u.w : cv.u.z;
    unsigned e0  = (p0 & 2u) ? a23 : a01;
    unsigned e1;
    if ((i1 & ~3u) == g) {
        unsigned p1 = i1 & 3u;
        unsigned b01 = (p1 & 1u) ? cv.u.y : cv.u.x;
        unsigned b23 = (p1 & 1u) ? cv.u.w : cv.u.z;
        e1 = (p1 & 2u) ? b23 : b01;
    } else {
        e1 = *(const unsigned*)(tl + i1);
    }
    h2 c0 = __builtin_bit_cast(h2, e0);
    h2 c1 = __builtin_bit_cast(h2, e1);
    v0 = make_float2((float)c0[0], (float)c0[1]);
    v1 = make_float2((float)c1[0], (float)c1[1]);
}

// full per-(point,level) encode -> packed h2 feature pair
__device__ __forceinline__ h2 encode_point(
    float px, float py, float pz, float s, int res, bool dense,
    const h2* __restrict__ tl)
{
    float fx = px * s + 0.5f, fy = py * s + 0.5f, fz = pz * s + 0.5f;
    float gx = floorf(fx), gy = floorf(fy), gz = floorf(fz);
    float wx = fx - gx, wy = fy - gy, wz = fz - gz;
    int cx = (int)gx, cy = (int)gy, cz = (int)gz;

    float2 vx0[4], vx1[4];             // combo j: y=(j>>1), z=(j&1)
    if (dense) {
        int r1 = res - 1;
        int x0 = min(cx, r1), x1 = min(cx + 1, r1);
        int y0 = min(cy, r1), y1 = min(cy + 1, r1);
        int z0 = min(cz, r1), z1 = min(cz + 1, r1);
        int rr = res * res;
        int bases[4] = {y0 * res + z0 * rr, y0 * res + z1 * rr,
                        y1 * res + z0 * rr, y1 * res + z1 * rr};
#pragma unroll
        for (int j = 0; j < 4; ++j)
            gather_pair(tl, (unsigned)(x0 + bases[j]), (unsigned)(x1 + bases[j]),
                        vx0[j], vx1[j]);
    } else {
        unsigned hy0 = (unsigned)cy * 2654435761u, hy1 = (unsigned)(cy + 1) * 2654435761u;
        unsigned hz0 = (unsigned)cz * 805459861u,  hz1 = (unsigned)(cz + 1) * 805459861u;
        unsigned Y[4] = {hy0 ^ hz0, hy0 ^ hz1, hy1 ^ hz0, hy1 ^ hz1};
        const unsigned M = T_SIZE - 1;
#pragma unroll
        for (int j = 0; j < 4; ++j)
            gather_pair(tl, ((unsigned)cx ^ Y[j]) & M,
                        ((unsigned)(cx + 1) ^ Y[j]) & M, vx0[j], vx1[j]);
    }

    float wx0 = 1.f - wx, wy0 = 1.f - wy, wz0 = 1.f - wz;
    float wyz[4] = {wy0 * wz0, wy0 * wz, wy * wz0, wy * wz};
    float f0 = 0.f, f1 = 0.f;
#pragma unroll
    for (int j = 0; j < 4; ++j) {
        float w0 = wx0 * wyz[j], w1 = wx * wyz[j];
        f0 += w0 * vx0[j].x + w1 * vx1[j].x;
        f1 += w0 * vx0[j].y + w1 * vx1[j].y;
    }
    h2 r; r[0] = (_Float16)f0; r[1] = (_Float16)f1;
    return r;
}

// ---------------- Kernel A (phase 1): hash levels lbase.. -> enc2 [16][N] ----
__global__ __launch_bounds__(256) void encode_kernel(
    const float* __restrict__ xs, const h2* __restrict__ table,
    h2* __restrict__ enc2, Levels lv, int lbase, int N)
{
    __shared__ float sx[768];
    const int i0 = blockIdx.x * 256;
    for (int t = threadIdx.x; t < 768; t += 256) sx[t] = xs[(size_t)i0 * 3 + t];
    __syncthreads();

    const int l = lbase + blockIdx.y;
    const int i = i0 + threadIdx.x;
    if (i >= N) return;
    h2 r = encode_point(sx[threadIdx.x * 3], sx[threadIdx.x * 3 + 1],
                        sx[threadIdx.x * 3 + 2], lv.scale[l], lv.res[l],
                        (lv.dense_mask >> l) & 1u, table + (size_t)l * T_SIZE);
    enc2[(size_t)l * N + i] = r;       // coalesced 4B store
}

// sorted variant (1 pt/thread, proven fastest). Only FINE levels (10..14) now:
// sorting doesn't help them, but enc2 order must match fused's staged reads.
__global__ __launch_bounds__(256) void encode_kernel_sorted(
    const float4* __restrict__ xs4, const h2* __restrict__ table,
    h2* __restrict__ enc2, Levels lv, int lbase, int N)
{
    const int i = blockIdx.x * 256 + threadIdx.x;
    if (i >= N) return;
    const int l = lbase + blockIdx.y;
    float4 q = xs4[i];
    h2 r = encode_point(q.x, q.y, q.z, lv.scale[l], lv.res[l],
                        (lv.dense_mask >> l) & 1u, table + (size_t)l * T_SIZE);
    enc2[(size_t)l * N + i] = r;       // coalesced 4B store
}

// generic 8-half fragment load (f16 direct dwordx4, or f32 + convert)
template <typename WT>
__device__ __forceinline__ h8 load_frag8(const WT* p) {
    if constexpr (sizeof(WT) == 2) {
        return *(const h8*)p;
    } else {
        h8 r;
#pragma unroll
        for (int j = 0; j < 8; ++j) r[j] = (_Float16)p[j];
        return r;
    }
}

// ------------- Kernel B (fused): encode levels {15,5-9,0-4} locally + MLP ---
// Sorted points make levels 5-9 L1-cheap -> encode them here instead of the
// enc2 round-trip (saves 40MB traffic). Level 15 issued FIRST (longest pole,
// random lines, no sharing). Only fine levels 10-14 staged from enc2.
template <typename WT, bool LOCAL, bool SORTED>
__global__ __launch_bounds__(256, 3) void fused_kernel(
    const float* __restrict__ xs, const float4* __restrict__ xs4,
    const h2* __restrict__ table16, const h2* __restrict__ enc2,
    const WT* __restrict__ w1, const WT* __restrict__ w2,
    const WT* __restrict__ w3, const float* __restrict__ w4,
    float* __restrict__ out, Levels lv, int N)
{
    constexpr int AR = 72;                          // 144B act rows, 16B-aligned
    __shared__ __align__(16) char smem[4 * 9216];   // per-wave: sEnc ∪ sAct
    __shared__ float sx[768];

    const int tid  = threadIdx.x;
    const int wave = tid >> 6;
    const int lane = tid & 63;
    const int lrow = lane & 15;
    const int quad = lane >> 4;
    const int base = blockIdx.x * 256;
    char* wmem = smem + wave * 9216;
    const f4 zero = {0.f, 0.f, 0.f, 0.f};

    float px, py, pz;
    unsigned oi = 0;
    if constexpr (SORTED) {
        float4 q = xs4[base + tid];
        px = q.x; py = q.y; pz = q.z;
        oi = __float_as_uint(q.w);
    } else {
        for (int t = tid; t < 768; t += 256) sx[t] = xs[(size_t)base * 3 + t];
        __syncthreads();
        px = sx[tid * 3]; py = sx[tid * 3 + 1]; pz = sx[tid * 3 + 2];
    }
    const int p = tid & 63;                         // local point in wave region

    // sEnc layout (transposed): byte = (l>>2)*1024 + p*16 + (l&3)*4
    if (LOCAL) {
#pragma unroll
        for (int l = 10; l < 15; ++l) {             // 5 coalesced 4B global loads
            h2 v = enc2[(size_t)l * N + base + tid];
            *(h2*)(wmem + ((l >> 2) << 10) + (p << 4) + ((l & 3) << 2)) = v;
        }
        const int LMAP[11] = {15, 5, 6, 7, 8, 9, 0, 1, 2, 3, 4};
#pragma unroll
        for (int s6 = 0; s6 < 11; ++s6) {
            const int l = LMAP[s6];
            h2 v = encode_point(px, py, pz, lv.scale[l], lv.res[l],
                                (lv.dense_mask >> l) & 1u,
                                table16 + (size_t)l * T_SIZE);
            *(h2*)(wmem + ((l >> 2) << 10) + (p << 4) + ((l & 3) << 2)) = v;
        }
    } else {
#pragma unroll
        for (int l = 0; l < 16; ++l) {
            h2 v = enc2[(size_t)l * N + base + tid];
            *(h2*)(wmem + ((l >> 2) << 10) + (p << 4) + ((l & 3) << 2)) = v;
        }
    }

    asm volatile("" ::: "memory");   // keep weight loads after encode (pressure)

    // weight A-frags (L2-hot) + packed w4
    h8 aW1[4];
#pragma unroll
    for (int tm = 0; tm < 4; ++tm)
        aW1[tm] = load_frag8(w1 + (tm * 16 + lrow) * 32 + quad * 8);
    h8 aW2[4][2], aW3[4][2];
#pragma unroll
    for (int tm = 0; tm < 4; ++tm)
#pragma unroll
        for (int km = 0; km < 2; ++km) {
            aW2[tm][km] = load_frag8(w2 + (tm * 16 + lrow) * 64 + km * 32 + quad * 8);
            aW3[tm][km] = load_frag8(w3 + (tm * 16 + lrow) * 64 + km * 32 + quad * 8);
        }
    h4 w4q[4];
#pragma unroll
    for (int tm = 0; tm < 4; ++tm)
#pragma unroll
        for (int r = 0; r < 4; ++r) w4q[tm][r] = (_Float16)w4[tm * 16 + quad * 4 + r];

    // pre-read ALL layer-1 B-frags BEFORE sAct overwrites the sEnc region.
    h8 bin[4];
#pragma unroll
    for (int t = 0; t < 4; ++t)
        bin[t] = *(const h8*)(wmem + (quad << 10) + ((t * 16 + lrow) << 4));

    _Float16* wAct = (_Float16*)wmem;               // local rows 0..63, stride AR

    // ---- Layer 1: D1 = W1 · enc^T ----
#pragma unroll
    for (int t = 0; t < 4; ++t) {
        const int arow = (t * 16 + lrow) * AR;
#pragma unroll
        for (int tm = 0; tm < 4; ++tm) {
            f4 acc = __builtin_amdgcn_mfma_f32_16x16x32_f16(aW1[tm], bin[t], zero, 0, 0, 0);
            h4 pk;
#pragma unroll
            for (int r = 0; r < 4; ++r) pk[r] = (_Float16)softplus10(acc[r]);
            *(h4*)&wAct[arow + tm * 16 + quad * 4] = pk;
        }
    }

    // ---- Layer 2: D2 = W2 · act1^T ----
#pragma unroll
    for (int t = 0; t < 4; ++t) {
        const int arow = (t * 16 + lrow) * AR;
        h8 b0 = *(const h8*)&wAct[arow + quad * 8];
        h8 b1 = *(const h8*)&wAct[arow + 32 + quad * 8];
        f4 accs[4];
#pragma unroll
        for (int tm = 0; tm < 4; ++tm) {
            f4 acc = __builtin_amdgcn_mfma_f32_16x16x32_f16(aW2[tm][0], b0, zero, 0, 0, 0);
            acc     = __builtin_amdgcn_mfma_f32_16x16x32_f16(aW2[tm][1], b1, acc,  0, 0, 0);
            accs[tm] = acc;
        }
#pragma unroll
        for (int tm = 0; tm < 4; ++tm) {
            h4 pk;
#pragma unroll
            for (int r = 0; r < 4; ++r) pk[r] = (_Float16)softplus10(accs[tm][r]);
            *(h4*)&wAct[arow + tm * 16 + quad * 4] = pk;
        }
    }

    // ---- Layer 3+4 fused: sdf = w4 · softplus(W3 · act2^T) ----
#pragma unroll
    for (int t = 0; t < 4; ++t) {
        const int arow = (t * 16 + lrow) * AR;
        h8 b0 = *(const h8*)&wAct[arow + quad * 8];
        h8 b1 = *(const h8*)&wAct[arow + 32 + quad * 8];
        float sum = 0.f;
#pragma unroll
        for (int tm = 0; tm < 4; ++tm) {
            f4 acc = __builtin_amdgcn_mfma_f32_16x16x32_f16(aW3[tm][0], b0, zero, 0, 0, 0);
            acc     = __builtin_amdgcn_mfma_f32_16x16x32_f16(aW3[tm][1], b1, acc,  0, 0, 0);
#pragma unroll
            for (int r = 0; r < 4; ++r)
                sum += (float)w4q[tm][r] * softplus10(acc[r]);
        }
        sum += __shfl_xor(sum, 16, 64);
        sum += __shfl_xor(sum, 32, 64);
        if constexpr (SORTED) {
            unsigned t_oi = __shfl(oi, t * 16 + lrow, 64);
            if (quad == 0) out[t_oi] = sum;
        } else {
            if (quad == 0)
                out[base + wave * 64 + t * 16 + lrow] = sum;
        }
    }
}

// Fallback encode (f32 table, all 16 levels) if workspace too small
__global__ __launch_bounds__(256) void encode_kernel_f32(
    const float* __restrict__ xs, const float2* __restrict__ table,
    h2* __restrict__ enc2, Levels lv, int N)
{
    const int i = blockIdx.x * 256 + threadIdx.x;
    const int l = blockIdx.y;
    if (i >= N) return;
    float px = xs[3 * i], py = xs[3 * i + 1], pz = xs[3 * i + 2];
    float s = lv.scale[l];
    int res = lv.res[l];
    float fx = px * s + 0.5f, fy = py * s + 0.5f, fz = pz * s + 0.5f;
    float gx = floorf(fx), gy = floorf(fy), gz = floorf(fz);
    float wx = fx - gx, wy = fy - gy, wz = fz - gz;
    int cx = (int)gx, cy = (int)gy, cz = (int)gz;
    unsigned idx[8];
    if ((lv.dense_mask >> l) & 1u) {
        int r1 = res - 1;
        int x0 = min(cx, r1), x1 = min(cx + 1, r1);
        int y0 = min(cy, r1), y1 = min(cy + 1, r1);
        int z0 = min(cz, r1), z1 = min(cz + 1, r1);
        int rr = res * res;
        idx[0] = x0 + y0 * res + z0 * rr; idx[1] = x0 + y0 * res + z1 * rr;
        idx[2] = x0 + y1 * res + z0 * rr; idx[3] = x0 + y1 * res + z1 * rr;
        idx[4] = x1 + y0 * res + z0 * rr; idx[5] = x1 + y0 * res + z1 * rr;
        idx[6] = x1 + y1 * res + z0 * rr; idx[7] = x1 + y1 * res + z1 * rr;
    } else {
        unsigned hx0 = (unsigned)cx, hx1 = (unsigned)(cx + 1);
        unsigned hy0 = (unsigned)cy * 2654435761u, hy1 = (unsigned)(cy + 1) * 2654435761u;
        unsigned hz0 = (unsigned)cz * 805459861u,  hz1 = (unsigned)(cz + 1) * 805459861u;
        idx[0] = (hx0^hy0^hz0) & (T_SIZE-1); idx[1] = (hx0^hy0^hz1) & (T_SIZE-1);
        idx[2] = (hx0^hy1^hz0) & (T_SIZE-1); idx[3] = (hx0^hy1^hz1) & (T_SIZE-1);
        idx[4] = (hx1^hy0^hz0) & (T_SIZE-1); idx[5] = (hx1^hy0^hz1) & (T_SIZE-1);
        idx[6] = (hx1^hy1^hz0) & (T_SIZE-1); idx[7] = (hx1^hy1^hz1) & (T_SIZE-1);
    }
    const float2* tl = table + (size_t)l * T_SIZE;
    float wx0 = 1.f - wx, wy0 = 1.f - wy, wz0 = 1.f - wz;
    float wcs[8] = {wx0*wy0*wz0, wx0*wy0*wz, wx0*wy*wz0, wx0*wy*wz,
                    wx*wy0*wz0,  wx*wy0*wz,  wx*wy*wz0,  wx*wy*wz};
    float f0 = 0.f, f1 = 0.f;
#pragma unroll
    for (int c = 0; c < 8; ++c) {
        float2 v = tl[idx[c]];
        f0 += wcs[c] * v.x; f1 += wcs[c] * v.y;
    }
    h2 r; r[0] = (_Float16)f0; r[1] = (_Float16)f1;
    enc2[(size_t)l * N + i] = r;
}

extern "C" void kernel_launch(void* const* d_in, const int* in_sizes, int n_in,
                              void* d_out, int out_size, void* d_ws, size_t ws_size,
                              hipStream_t stream) {
    const float* x     = (const float*)d_in[0];
    const float* table = (const float*)d_in[1];
    const float* w1    = (const float*)d_in[2];
    const float* w2    = (const float*)d_in[3];
    const float* w3    = (const float*)d_in[4];
    const float* w4    = (const float*)d_in[5];
    float* out = (float*)d_out;
    const int N = in_sizes[0] / 3;                 // 1<<20

    Levels lv;
    lv.dense_mask = 0;
    const double pls = exp2(log2(2048.0 / 16.0) / 15.0);
    const double lg  = log2(pls);
    for (int l = 0; l < 16; ++l) {
        double sc = exp2((double)l * lg) * 16.0 - 1.0;
        int res = (int)ceil(sc) + 1;
        lv.scale[l] = (float)sc;
        lv.res[l]   = res;
        if ((long long)res * res * res <= (long long)T_SIZE) lv.dense_mask |= (1u << l);
    }

    const size_t encBytes   = (size_t)16 * N * 4;        // 64 MB ([16][N] h2)
    const size_t tableBytes = (size_t)16 * T_SIZE * 4;   // 33.5 MB f16 table
    const size_t whBytes    = 32768;                     // 10240 f16 weights
    const size_t sx4Bytes   = (size_t)N * 16;            // 16 MB sorted float4
    h2* enc2 = (h2*)d_ws;

    const int ptBlocks = (N + 255) / 256;                // 4096

    if (ws_size >= encBytes + tableBytes + whBytes + sx4Bytes
        && N == NBLK * 8192) {
        h2* table16    = (h2*)((char*)d_ws + encBytes);
        _Float16* wh   = (_Float16*)((char*)d_ws + encBytes + tableBytes);
        float4* sx4    = (float4*)((char*)d_ws + encBytes + tableBytes + whBytes);
        // M/Ms live inside enc2's level-0..9 region (never written here:
        // fused computes levels 0-9 & 15 locally; encode writes only 10..14).
        unsigned* M  = (unsigned*)d_ws;                               // 256KB
        unsigned* Ms = (unsigned*)((char*)d_ws + 512 * 1024);         // 256KB

        const int total4 = 16 * T_SIZE / 4;              // 2,097,152
        const int convBlocks = (total4 + 10240 + 255) / 256;
        // convert + weights + hist (extra NBLK blocks, overlapped)
        hipLaunchKernelGGL(convert_kernel, dim3(convBlocks + NBLK), dim3(256), 0,
                           stream, (const float2*)table, table16, total4,
                           w1, w2, w3, wh, x, M, N);
        hipLaunchKernelGGL(scan_kernel, dim3(1), dim3(1024), 0, stream, M, Ms);
        hipLaunchKernelGGL(cscatter_kernel, dim3(NBLK), dim3(256), 0, stream,
                           x, Ms, sx4, N);
        hipLaunchKernelGGL(refine_kernel, dim3(CB), dim3(256), 0, stream,
                           sx4, Ms, N);

        // phase 1: FINE hash levels 10..14 only, sorted order
        hipLaunchKernelGGL(encode_kernel_sorted, dim3(ptBlocks, 5), dim3(256),
                           0, stream, (const float4*)sx4, (const h2*)table16,
                           enc2, lv, 10, N);
        // phase 2: fused local-encode {15,5-9,0-4} + MLP, scatter to out[orig]
        hipLaunchKernelGGL((fused_kernel<_Float16, true, true>), dim3(ptBlocks), dim3(256),
                           0, stream, x, (const float4*)sx4, (const h2*)table16,
                           (const h2*)enc2, wh, wh + 2048, wh + 6144, w4, out, lv, N);
    } else if (ws_size >= encBytes + tableBytes + whBytes) {
        h2* table16 = (h2*)((char*)d_ws + encBytes);
        _Float16* wh = (_Float16*)((char*)d_ws + encBytes + tableBytes);
        const int total4 = 16 * T_SIZE / 4;              // 2,097,152
        const int convBlocks = (total4 + 10240 + 255) / 256;
        hipLaunchKernelGGL(convert_kernel, dim3(convBlocks), dim3(256), 0, stream,
                           (const float2*)table, table16, total4, w1, w2, w3, wh,
                           x, (unsigned*)nullptr, N);
        hipLaunchKernelGGL(encode_kernel, dim3(ptBlocks, 5), dim3(256), 0, stream,
                           x, (const h2*)table16, enc2, lv, 10, N);
        hipLaunchKernelGGL((fused_kernel<_Float16, true, false>), dim3(ptBlocks), dim3(256),
                           0, stream, x, (const float4*)nullptr, (const h2*)table16,
                           (const h2*)enc2, wh, wh + 2048, wh + 6144, w4, out, lv, N);
    } else {
        hipLaunchKernelGGL(encode_kernel_f32, dim3(ptBlocks, 16), dim3(256), 0, stream,
                           x, (const float2*)table, enc2, lv, N);
        hipLaunchKernelGGL((fused_kernel<float, false, false>), dim3(ptBlocks), dim3(256),
                           0, stream, x, (const float4*)nullptr, (const h2*)nullptr,
                           (const h2*)enc2, w1, w2, w3, w4, out, lv, N);
    }
}